// Round 1
// baseline (179.340 us; speedup 1.0000x reference)
//
#include <hip/hip_runtime.h>
#include <stdint.h>

typedef unsigned short u16;
typedef __bf16 bf16_t;
typedef bf16_t bf16x8 __attribute__((ext_vector_type(8)));
typedef float f32x4 __attribute__((ext_vector_type(4)));

static constexpr int P = 65536;  // H*W; D = C = 256

__device__ __forceinline__ float bfbits2f(uint32_t b) {
    union { uint32_t i; float f; } u; u.i = b << 16; return u.f;
}
__device__ __forceinline__ u16 f2bf(float f) {
    union { float f; uint32_t i; } u; u.f = f;
    uint32_t x = u.i + 0x7FFFu + ((u.i >> 16) & 1u);   // RNE
    return (u16)(x >> 16);
}
__device__ __forceinline__ uint32_t pack2(float a, float b) {
    return (uint32_t)f2bf(a) | ((uint32_t)f2bf(b) << 16);
}

// Runtime input-dtype sniff (insurance; verdict on this harness: f32).
__device__ __forceinline__ int detect_bf16_input(const void* Xg) {
    const uint32_t* Xu = (const uint32_t*)Xg;
    const int lane = (int)(threadIdx.x & 63);
    const uint32_t v = Xu[(size_t)lane * 131071u];
    const uint32_t e = (v >> 7) & 0xFFu;
    unsigned long long m = __ballot(e >= 96u && e <= 135u);
    return __popcll(m) >= 40;
}

// Kernel 1: rs[c] = scale[c]*5/max(||w_c||,1e-8)  AND  W -> bf16 row image.
// The bf16 image lets every gemm block read A fragments straight from L2
// (16 B per fragment), killing the per-block f32->bf16 conversion that was
// ~60% of the gemm's staging VALU. Same f2bf RNE as before -> bit-identical A.
__global__ __launch_bounds__(64) void coshead_prep(
    const void* __restrict__ Xg, const void* __restrict__ Wg,
    const void* __restrict__ Sg, float* __restrict__ rs_ws,
    u16* __restrict__ wbf)
{
    const int c    = (int)blockIdx.x;
    const int lane = (int)threadIdx.x;
    const int bf   = detect_bf16_input(Xg);
    float s;
    uint2 packed;
    if (bf) {
        const uint2 v = *(const uint2*)((const u16*)Wg + (size_t)c * 256 + lane * 4);
        const float a = bfbits2f(v.x & 0xFFFFu), b = bfbits2f(v.x >> 16);
        const float d = bfbits2f(v.y & 0xFFFFu), e = bfbits2f(v.y >> 16);
        s = a * a + b * b + d * d + e * e;
        packed = v;
    } else {
        const f32x4 v = *(const f32x4*)((const float*)Wg + (size_t)c * 256 + lane * 4);
        s = v[0] * v[0] + v[1] * v[1] + v[2] * v[2] + v[3] * v[3];
        packed.x = pack2(v[0], v[1]);
        packed.y = pack2(v[2], v[3]);
    }
    *(uint2*)(wbf + (size_t)c * 256 + lane * 4) = packed;
    s += __shfl_xor(s, 1);  s += __shfl_xor(s, 2);  s += __shfl_xor(s, 4);
    s += __shfl_xor(s, 8);  s += __shfl_xor(s, 16); s += __shfl_xor(s, 32);
    if (lane == 0) {
        const float sc = bf ? bfbits2f((uint32_t)((const u16*)Sg)[c])
                            : ((const float*)Sg)[c];
        rs_ws[c] = sc * 5.0f / fmaxf(sqrtf(s), 1e-8f);
    }
}

// Kernel 2: out[c,p] = (W@X)[c,p] * rs[c] / max(||x_p||,1e-8), f32 out.
// 256 classes x 64 pixels per block, BK=64, 4 waves; MFMA 16x16x32_bf16.
// Changes vs prior version:
//  - A fragments loaded DIRECTLY from the L2-resident bf16 W image (each wave
//    only touches its own 64 rows -> no sA, no A ds traffic, no A conversion).
//  - sB double-buffered (2 x 8 KB); X loads for kc+1 are issued BEFORE the
//    barrier and consumed after the MFMA phase (T14 issue-early/write-late).
//  - ONE __syncthreads per kc (dbuf makes the trailing barrier unnecessary:
//    iteration kc+2's writes to buf[kc&1] are ordered after barrier(kc+1),
//    which is after every wave's MFMA reads of buf[kc&1] in program order).
__global__ __launch_bounds__(256, 4) void coshead_gemm(
    const void* __restrict__ Xg_, const u16* __restrict__ Wbf,
    const float* __restrict__ rs_ws, float* __restrict__ Og)
{
    __shared__ char smem_[16384];      // sB dbuf: [2][64 pix][8 granules x 16 B]

    const int t  = (int)threadIdx.x;
    const int l  = t & 63;
    const int w  = t >> 6;
    const int p0 = (int)blockIdx.x * 64;
    const int bf = detect_bf16_input(Xg_);

    const int g    = t & 7;      // pixel octet
    const int r    = t >> 3;     // k-pair row 0..31
    const int m16  = l & 15;
    const int quad = l >> 4;

    float ssq[8];
#pragma unroll
    for (int j = 0; j < 8; ++j) ssq[j] = 0.f;
    f32x4 acc[4][4];
#pragma unroll
    for (int a = 0; a < 4; ++a)
#pragma unroll
        for (int b = 0; b < 4; ++b)
#pragma unroll
            for (int i = 0; i < 4; ++i) acc[a][b][i] = 0.f;

    // f32-path X prefetch registers (2 k-rows x 8 pixels)
    f32x4 rA, rB, rC, rD;
    if (!bf) {
        const float* xp = (const float*)Xg_ + (size_t)(2 * r) * P + p0 + g * 8;
        rA = *(const f32x4*)xp;
        rB = *(const f32x4*)(xp + 4);
        rC = *(const f32x4*)(xp + P);
        rD = *(const f32x4*)(xp + P + 4);
    }

    const u16* wrow = Wbf + (size_t)(w * 64 + m16) * 256 + quad * 8;

    for (int kc = 0; kc < 4; ++kc) {
        char* sBw = smem_ + (kc & 1) * 8192;
        if (bf) {
            // ---- insurance path: bf16 input, load+pack in-loop (no pipeline) ----
            const u16* xp = (const u16*)Xg_ + (size_t)(2 * r + kc * 64) * P + p0 + g * 8;
            const uint4 v0 = *(const uint4*)xp;
            const uint4 v1 = *(const uint4*)(xp + P);
            const uint32_t e0[4] = {v0.x, v0.y, v0.z, v0.w};
            const uint32_t e1[4] = {v1.x, v1.y, v1.z, v1.w};
#pragma unroll
            for (int d = 0; d < 4; ++d) {
                const float f00 = bfbits2f(e0[d] & 0xFFFFu), f01 = bfbits2f(e0[d] >> 16);
                const float f10 = bfbits2f(e1[d] & 0xFFFFu), f11 = bfbits2f(e1[d] >> 16);
                ssq[2 * d]     += f00 * f00 + f10 * f10;
                ssq[2 * d + 1] += f01 * f01 + f11 * f11;
                const uint32_t d0 = (e0[d] & 0xFFFFu) | (e1[d] << 16);
                const uint32_t d1 = (e0[d] >> 16) | (e1[d] & 0xFFFF0000u);
                const int pj0 = g * 8 + 2 * d, pj1 = pj0 + 1;
                *(uint32_t*)(sBw + pj0 * 128 + (((r >> 2) ^ (pj0 & 7) ^ g) * 16) + (r & 3) * 4) = d0;
                *(uint32_t*)(sBw + pj1 * 128 + (((r >> 2) ^ (pj1 & 7) ^ g) * 16) + (r & 3) * 4) = d1;
            }
        } else {
            // ---- f32 path: consume prefetched regs (ssq + pack + swizzled write) ----
            const float f0[8] = {rA[0], rA[1], rA[2], rA[3], rB[0], rB[1], rB[2], rB[3]};
            const float f1[8] = {rC[0], rC[1], rC[2], rC[3], rD[0], rD[1], rD[2], rD[3]};
#pragma unroll
            for (int j = 0; j < 8; ++j) {
                ssq[j] += f0[j] * f0[j] + f1[j] * f1[j];
                const int pix = g * 8 + j;
                *(uint32_t*)(sBw + pix * 128 + (((r >> 2) ^ (pix & 7) ^ g) * 16) + (r & 3) * 4) =
                    pack2(f0[j], f1[j]);
            }
            // issue next kc's X loads NOW; they drain under barrier+MFMA
            if (kc < 3) {
                const float* xp = (const float*)Xg_ + (size_t)(2 * r + (kc + 1) * 64) * P + p0 + g * 8;
                rA = *(const f32x4*)xp;
                rB = *(const f32x4*)(xp + 4);
                rC = *(const f32x4*)(xp + P);
                rD = *(const f32x4*)(xp + P + 4);
            }
        }
        __syncthreads();

        // ---- MFMA: A direct from global bf16 image, B from LDS ----
        const u16* wk = wrow + kc * 64;
#pragma unroll
        for (int kk = 0; kk < 2; ++kk) {
            bf16x8 af[4], bfr[4];
#pragma unroll
            for (int tm = 0; tm < 4; ++tm)
                af[tm] = *(const bf16x8*)(wk + tm * 16 * 256 + kk * 32);
#pragma unroll
            for (int tn = 0; tn < 4; ++tn) {
                const int pix = tn * 16 + m16;
                bfr[tn] = *(const bf16x8*)(sBw + pix * 128 +
                           (((kk * 4 + quad) ^ (pix & 7) ^ (pix >> 3)) * 16));
            }
#pragma unroll
            for (int tm = 0; tm < 4; ++tm)
#pragma unroll
                for (int tn = 0; tn < 4; ++tn)
                    acc[tm][tn] = __builtin_amdgcn_mfma_f32_16x16x32_bf16(
                        af[tm], bfr[tn], acc[tm][tn], 0, 0, 0);
        }
        // no trailing barrier: double-buffered sB
    }

    // ---- epilogue: x-norms via LDS transpose-reduce (reuse smem_) ----
    __syncthreads();
    float* xs   = (float*)smem_;            // [32][64] partial ssq (8 KB)
    float* xinv = (float*)(smem_ + 8192);   // [64]
#pragma unroll
    for (int j = 0; j < 8; ++j) xs[r * 64 + g * 8 + j] = ssq[j];
    __syncthreads();
    if (t < 64) {
        float sx = 0.f;
#pragma unroll
        for (int rr = 0; rr < 32; ++rr) sx += xs[rr * 64 + t];
        xinv[t] = 1.0f / fmaxf(sqrtf(sx), 1e-8f);
    }
    __syncthreads();

    // ---- scaled f32 store. class = w*64+tm*16+quad*4+i ; pixel = p0+tn*16+m16 ----
    float inv4[4];
#pragma unroll
    for (int tn = 0; tn < 4; ++tn) inv4[tn] = xinv[tn * 16 + m16];
#pragma unroll
    for (int tm = 0; tm < 4; ++tm) {
        const int cbase = w * 64 + tm * 16 + quad * 4;
        const f32x4 rs4 = *(const f32x4*)(rs_ws + cbase);
#pragma unroll
        for (int tn = 0; tn < 4; ++tn) {
#pragma unroll
            for (int i = 0; i < 4; ++i) {
                Og[(size_t)(cbase + i) * P + p0 + tn * 16 + m16] =
                    acc[tm][tn][i] * rs4[i] * inv4[tn];
            }
        }
    }
}

extern "C" void kernel_launch(void* const* d_in, const int* in_sizes, int n_in,
                              void* d_out, int out_size, void* d_ws, size_t ws_size,
                              hipStream_t stream) {
    (void)out_size; (void)ws_size;
    const void* X = d_in[0];
    const void* W = d_in[1];
    const void* S = d_in[2];
    for (int i = 0; i < n_in; ++i) {
        if (in_sizes[i] == 256 * 65536) X = d_in[i];
        else if (in_sizes[i] == 256 * 256) W = d_in[i];
        else if (in_sizes[i] == 256)      S = d_in[i];
    }
    float* rs  = (float*)d_ws;
    u16*   wbf = (u16*)((char*)d_ws + 1024);   // 128 KB bf16 W image
    coshead_prep<<<dim3(256), dim3(64), 0, stream>>>(X, W, S, rs, wbf);
    coshead_gemm<<<dim3(1024), dim3(256), 0, stream>>>(X, wbf, rs, (float*)d_out);
}

// Round 2
// 145.553 us; speedup vs baseline: 1.2321x; 1.2321x over previous
//
#include <hip/hip_runtime.h>
#include <stdint.h>

typedef unsigned short u16;
typedef __bf16 bf16_t;
typedef bf16_t bf16x8 __attribute__((ext_vector_type(8)));
typedef float f32x4 __attribute__((ext_vector_type(4)));

static constexpr int P = 65536;  // H*W; D = C = 256

__device__ __forceinline__ float bfbits2f(uint32_t b) {
    union { uint32_t i; float f; } u; u.i = b << 16; return u.f;
}
__device__ __forceinline__ u16 f2bf(float f) {
    union { float f; uint32_t i; } u; u.f = f;
    uint32_t x = u.i + 0x7FFFu + ((u.i >> 16) & 1u);   // RNE
    return (u16)(x >> 16);
}
__device__ __forceinline__ uint32_t pack2(float a, float b) {
    return (uint32_t)f2bf(a) | ((uint32_t)f2bf(b) << 16);
}

// Runtime input-dtype sniff (insurance; verdict on this harness: f32).
__device__ __forceinline__ int detect_bf16_input(const void* Xg) {
    const uint32_t* Xu = (const uint32_t*)Xg;
    const int lane = (int)(threadIdx.x & 63);
    const uint32_t v = Xu[(size_t)lane * 131071u];
    const uint32_t e = (v >> 7) & 0xFFu;
    unsigned long long m = __ballot(e >= 96u && e <= 135u);
    return __popcll(m) >= 40;
}

// Kernel 1: rs[c] = scale[c]*5/max(||w_c||,1e-8)  AND  W -> bf16 row image.
__global__ __launch_bounds__(64) void coshead_prep(
    const void* __restrict__ Xg, const void* __restrict__ Wg,
    const void* __restrict__ Sg, float* __restrict__ rs_ws,
    u16* __restrict__ wbf)
{
    const int c    = (int)blockIdx.x;
    const int lane = (int)threadIdx.x;
    const int bf   = detect_bf16_input(Xg);
    float s;
    uint2 packed;
    if (bf) {
        const uint2 v = *(const uint2*)((const u16*)Wg + (size_t)c * 256 + lane * 4);
        const float a = bfbits2f(v.x & 0xFFFFu), b = bfbits2f(v.x >> 16);
        const float d = bfbits2f(v.y & 0xFFFFu), e = bfbits2f(v.y >> 16);
        s = a * a + b * b + d * d + e * e;
        packed = v;
    } else {
        const f32x4 v = *(const f32x4*)((const float*)Wg + (size_t)c * 256 + lane * 4);
        s = v[0] * v[0] + v[1] * v[1] + v[2] * v[2] + v[3] * v[3];
        packed.x = pack2(v[0], v[1]);
        packed.y = pack2(v[2], v[3]);
    }
    *(uint2*)(wbf + (size_t)c * 256 + lane * 4) = packed;
    s += __shfl_xor(s, 1);  s += __shfl_xor(s, 2);  s += __shfl_xor(s, 4);
    s += __shfl_xor(s, 8);  s += __shfl_xor(s, 16); s += __shfl_xor(s, 32);
    if (lane == 0) {
        const float sc = bf ? bfbits2f((uint32_t)((const u16*)Sg)[c])
                            : ((const float*)Sg)[c];
        rs_ws[c] = sc * 5.0f / fmaxf(sqrtf(s), 1e-8f);
    }
}

// Kernel 2: out[c,p] = (W@X)[c,p] * rs[c] / max(||x_p||,1e-8), f32 out.
// 256 classes x 64 pixels per block, BK=64, 4 waves; MFMA 16x16x32_bf16.
//  - A fragments loaded DIRECTLY from the L2-resident bf16 W image.
//  - sB double-buffered (2 x 8 KB); ONE __syncthreads per kc.
//  - X loads for kc+1 issued before the barrier (T14), drain under MFMA.
//  - launch_bounds(256,3): ~168-reg budget -> NO spill (round-1 lesson:
//    (256,4)'s 128-reg cap spilled acc -> +150 MB scratch traffic, 2x dur).
__global__ __launch_bounds__(256, 3) void coshead_gemm(
    const void* __restrict__ Xg_, const u16* __restrict__ Wbf,
    const float* __restrict__ rs_ws, float* __restrict__ Og)
{
    __shared__ char smem_[16384];      // sB dbuf: [2][64 pix][8 granules x 16 B]

    const int t  = (int)threadIdx.x;
    const int l  = t & 63;
    const int w  = t >> 6;
    const int p0 = (int)blockIdx.x * 64;
    const int bf = detect_bf16_input(Xg_);

    const int g    = t & 7;      // pixel octet
    const int r    = t >> 3;     // k-pair row 0..31
    const int m16  = l & 15;
    const int quad = l >> 4;

    float ssq[8];
#pragma unroll
    for (int j = 0; j < 8; ++j) ssq[j] = 0.f;
    f32x4 acc[4][4];
#pragma unroll
    for (int a = 0; a < 4; ++a)
#pragma unroll
        for (int b = 0; b < 4; ++b)
#pragma unroll
            for (int i = 0; i < 4; ++i) acc[a][b][i] = 0.f;

    // f32-path X prefetch registers (2 k-rows x 8 pixels)
    f32x4 rA, rB, rC, rD;
    if (!bf) {
        const float* xp = (const float*)Xg_ + (size_t)(2 * r) * P + p0 + g * 8;
        rA = *(const f32x4*)xp;
        rB = *(const f32x4*)(xp + 4);
        rC = *(const f32x4*)(xp + P);
        rD = *(const f32x4*)(xp + P + 4);
    }

    const u16* wrow = Wbf + (size_t)(w * 64 + m16) * 256 + quad * 8;

    for (int kc = 0; kc < 4; ++kc) {
        char* sBw = smem_ + (kc & 1) * 8192;
        if (bf) {
            // ---- insurance path: bf16 input, load+pack in-loop ----
            const u16* xp = (const u16*)Xg_ + (size_t)(2 * r + kc * 64) * P + p0 + g * 8;
            const uint4 v0 = *(const uint4*)xp;
            const uint4 v1 = *(const uint4*)(xp + P);
            const uint32_t e0[4] = {v0.x, v0.y, v0.z, v0.w};
            const uint32_t e1[4] = {v1.x, v1.y, v1.z, v1.w};
#pragma unroll
            for (int d = 0; d < 4; ++d) {
                const float f00 = bfbits2f(e0[d] & 0xFFFFu), f01 = bfbits2f(e0[d] >> 16);
                const float f10 = bfbits2f(e1[d] & 0xFFFFu), f11 = bfbits2f(e1[d] >> 16);
                ssq[2 * d]     += f00 * f00 + f10 * f10;
                ssq[2 * d + 1] += f01 * f01 + f11 * f11;
                const uint32_t d0 = (e0[d] & 0xFFFFu) | (e1[d] << 16);
                const uint32_t d1 = (e0[d] >> 16) | (e1[d] & 0xFFFF0000u);
                const int pj0 = g * 8 + 2 * d, pj1 = pj0 + 1;
                *(uint32_t*)(sBw + pj0 * 128 + (((r >> 2) ^ (pj0 & 7) ^ g) * 16) + (r & 3) * 4) = d0;
                *(uint32_t*)(sBw + pj1 * 128 + (((r >> 2) ^ (pj1 & 7) ^ g) * 16) + (r & 3) * 4) = d1;
            }
        } else {
            // ---- f32 path: consume prefetched regs (ssq + pack + swizzled write) ----
            const float f0[8] = {rA[0], rA[1], rA[2], rA[3], rB[0], rB[1], rB[2], rB[3]};
            const float f1[8] = {rC[0], rC[1], rC[2], rC[3], rD[0], rD[1], rD[2], rD[3]};
#pragma unroll
            for (int j = 0; j < 8; ++j) {
                ssq[j] += f0[j] * f0[j] + f1[j] * f1[j];
                const int pix = g * 8 + j;
                *(uint32_t*)(sBw + pix * 128 + (((r >> 2) ^ (pix & 7) ^ g) * 16) + (r & 3) * 4) =
                    pack2(f0[j], f1[j]);
            }
            // issue next kc's X loads NOW; they drain under barrier+MFMA
            if (kc < 3) {
                const float* xp = (const float*)Xg_ + (size_t)(2 * r + (kc + 1) * 64) * P + p0 + g * 8;
                rA = *(const f32x4*)xp;
                rB = *(const f32x4*)(xp + 4);
                rC = *(const f32x4*)(xp + P);
                rD = *(const f32x4*)(xp + P + 4);
            }
        }
        __syncthreads();

        // ---- MFMA: A direct from global bf16 image (all 8 frags issued first
        //      so L2 latency overlaps the LDS reads), B from LDS ----
        const u16* wk = wrow + kc * 64;
        bf16x8 af[2][4];
#pragma unroll
        for (int kk = 0; kk < 2; ++kk)
#pragma unroll
            for (int tm = 0; tm < 4; ++tm)
                af[kk][tm] = *(const bf16x8*)(wk + tm * 16 * 256 + kk * 32);
#pragma unroll
        for (int kk = 0; kk < 2; ++kk) {
            bf16x8 bfr[4];
#pragma unroll
            for (int tn = 0; tn < 4; ++tn) {
                const int pix = tn * 16 + m16;
                bfr[tn] = *(const bf16x8*)(sBw + pix * 128 +
                           (((kk * 4 + quad) ^ (pix & 7) ^ (pix >> 3)) * 16));
            }
#pragma unroll
            for (int tm = 0; tm < 4; ++tm)
#pragma unroll
                for (int tn = 0; tn < 4; ++tn)
                    acc[tm][tn] = __builtin_amdgcn_mfma_f32_16x16x32_bf16(
                        af[kk][tm], bfr[tn], acc[tm][tn], 0, 0, 0);
        }
        // no trailing barrier: double-buffered sB
    }

    // ---- epilogue: x-norms via LDS transpose-reduce (reuse smem_) ----
    __syncthreads();
    float* xs   = (float*)smem_;            // [32][64] partial ssq (8 KB)
    float* xinv = (float*)(smem_ + 8192);   // [64]
#pragma unroll
    for (int j = 0; j < 8; ++j) xs[r * 64 + g * 8 + j] = ssq[j];
    __syncthreads();
    if (t < 64) {
        float sx = 0.f;
#pragma unroll
        for (int rr = 0; rr < 32; ++rr) sx += xs[rr * 64 + t];
        xinv[t] = 1.0f / fmaxf(sqrtf(sx), 1e-8f);
    }
    __syncthreads();

    // ---- scaled f32 store. class = w*64+tm*16+quad*4+i ; pixel = p0+tn*16+m16 ----
    float inv4[4];
#pragma unroll
    for (int tn = 0; tn < 4; ++tn) inv4[tn] = xinv[tn * 16 + m16];
#pragma unroll
    for (int tm = 0; tm < 4; ++tm) {
        const int cbase = w * 64 + tm * 16 + quad * 4;
        const f32x4 rs4 = *(const f32x4*)(rs_ws + cbase);
#pragma unroll
        for (int tn = 0; tn < 4; ++tn) {
#pragma unroll
            for (int i = 0; i < 4; ++i) {
                Og[(size_t)(cbase + i) * P + p0 + tn * 16 + m16] =
                    acc[tm][tn][i] * rs4[i] * inv4[tn];
            }
        }
    }
}

extern "C" void kernel_launch(void* const* d_in, const int* in_sizes, int n_in,
                              void* d_out, int out_size, void* d_ws, size_t ws_size,
                              hipStream_t stream) {
    (void)out_size; (void)ws_size;
    const void* X = d_in[0];
    const void* W = d_in[1];
    const void* S = d_in[2];
    for (int i = 0; i < n_in; ++i) {
        if (in_sizes[i] == 256 * 65536) X = d_in[i];
        else if (in_sizes[i] == 256 * 256) W = d_in[i];
        else if (in_sizes[i] == 256)      S = d_in[i];
    }
    float* rs  = (float*)d_ws;
    u16*   wbf = (u16*)((char*)d_ws + 1024);   // 128 KB bf16 W image
    coshead_prep<<<dim3(256), dim3(64), 0, stream>>>(X, W, S, rs, wbf);
    coshead_gemm<<<dim3(1024), dim3(256), 0, stream>>>(X, wbf, rs, (float*)d_out);
}

// Round 3
// 139.557 us; speedup vs baseline: 1.2851x; 1.0430x over previous
//
#include <hip/hip_runtime.h>
#include <stdint.h>

typedef unsigned short u16;
typedef __bf16 bf16_t;
typedef bf16_t bf16x8 __attribute__((ext_vector_type(8)));
typedef float f32x4 __attribute__((ext_vector_type(4)));

static constexpr int P = 65536;  // H*W; D = C = 256

__device__ __forceinline__ float bfbits2f(uint32_t b) {
    union { uint32_t i; float f; } u; u.i = b << 16; return u.f;
}
__device__ __forceinline__ u16 f2bf(float f) {
    union { float f; uint32_t i; } u; u.f = f;
    uint32_t x = u.i + 0x7FFFu + ((u.i >> 16) & 1u);   // RNE
    return (u16)(x >> 16);
}
__device__ __forceinline__ uint32_t pack2(float a, float b) {
    return (uint32_t)f2bf(a) | ((uint32_t)f2bf(b) << 16);
}

// Runtime input-dtype sniff (insurance; verdict on this harness: f32).
__device__ __forceinline__ int detect_bf16_input(const void* Xg) {
    const uint32_t* Xu = (const uint32_t*)Xg;
    const int lane = (int)(threadIdx.x & 63);
    const uint32_t v = Xu[(size_t)lane * 131071u];
    const uint32_t e = (v >> 7) & 0xFFu;
    unsigned long long m = __ballot(e >= 96u && e <= 135u);
    return __popcll(m) >= 40;
}

// Kernel 1: rs[c] = scale[c]*5/max(||w_c||,1e-8)  AND  W -> bf16 row image
// (row-major, 256 u16 per row). Gemm stages A from this image with
// global_load_lds -> zero conversion VALU per block.
__global__ __launch_bounds__(64) void coshead_prep(
    const void* __restrict__ Xg, const void* __restrict__ Wg,
    const void* __restrict__ Sg, float* __restrict__ rs_ws,
    u16* __restrict__ wbf)
{
    const int c    = (int)blockIdx.x;
    const int lane = (int)threadIdx.x;
    const int bf   = detect_bf16_input(Xg);
    float s;
    uint2 packed;
    if (bf) {
        const uint2 v = *(const uint2*)((const u16*)Wg + (size_t)c * 256 + lane * 4);
        const float a = bfbits2f(v.x & 0xFFFFu), b = bfbits2f(v.x >> 16);
        const float d = bfbits2f(v.y & 0xFFFFu), e = bfbits2f(v.y >> 16);
        s = a * a + b * b + d * d + e * e;
        packed = v;
    } else {
        const f32x4 v = *(const f32x4*)((const float*)Wg + (size_t)c * 256 + lane * 4);
        s = v[0] * v[0] + v[1] * v[1] + v[2] * v[2] + v[3] * v[3];
        packed.x = pack2(v[0], v[1]);
        packed.y = pack2(v[2], v[3]);
    }
    *(uint2*)(wbf + (size_t)c * 256 + lane * 4) = packed;
    s += __shfl_xor(s, 1);  s += __shfl_xor(s, 2);  s += __shfl_xor(s, 4);
    s += __shfl_xor(s, 8);  s += __shfl_xor(s, 16); s += __shfl_xor(s, 32);
    if (lane == 0) {
        const float sc = bf ? bfbits2f((uint32_t)((const u16*)Sg)[c])
                            : ((const float*)Sg)[c];
        rs_ws[c] = sc * 5.0f / fmaxf(sqrtf(s), 1e-8f);
    }
}

// Kernel 2: out[c,p] = (W@X)[c,p] * rs[c] / max(||x_p||,1e-8), f32 out.
// Round-0 skeleton (proven 48us): 2 barriers/kc, sA+sB in LDS, MFMA 16x16x32.
// Changes, each removing a measured round-0/2 cost:
//  - sA staged via global_load_lds from bf16 W image (8 x 1KB wave-issues/kc):
//    no pack2, no staging regs. Swizzle via per-lane SOURCE address (linear
//    LDS dest); read-side formulas identical to round 0.
//  - NO af hoist (round-2 spill source). Fragments read per-kk from LDS.
//  - T14: B loads for kc+1 issued AFTER the leading barrier -> their drain
//    happens at the trailing barrier, hidden under the MFMA phase.
__global__ __launch_bounds__(256, 3) void coshead_gemm(
    const void* __restrict__ Xg_, const u16* __restrict__ Wbf,
    const float* __restrict__ rs_ws, float* __restrict__ Og)
{
    __shared__ char smem_[32768 + 8192];
    char* sA = smem_;            // [256 rows][8 slots x 16 B]; slot s holds granule s^(row&7)
    char* sB = smem_ + 32768;    // [64 pix][8 granules x 16 B], swizzled

    const int t  = (int)threadIdx.x;
    const int l  = t & 63;
    const int w  = t >> 6;
    const int p0 = (int)blockIdx.x * 64;
    const int bf = detect_bf16_input(Xg_);

    const int g    = t & 7;      // pixel octet
    const int r    = t >> 3;     // k-pair row 0..31
    const int m16  = l & 15;
    const int quad = l >> 4;

    // sA staging map: call j covers rows j*32 + w*8 .. +7 (1 KB, lane-linear dest).
    // lane l -> row_local = l>>3, slot = l&7; source granule = slot ^ (row&7),
    // and row&7 == l>>3, so the swizzle is a per-lane constant.
    const int lrow = l >> 3;
    const int gsl  = (l & 7) ^ lrow;
    const u16* wsrc = Wbf + ((size_t)(w * 8 + lrow) << 8) + gsl * 8;
    char* ldsA = sA + w * 1024;   // wave-uniform; + j*4096 per call

    float ssq[8];
#pragma unroll
    for (int j = 0; j < 8; ++j) ssq[j] = 0.f;
    f32x4 acc[4][4];
#pragma unroll
    for (int a = 0; a < 4; ++a)
#pragma unroll
        for (int b = 0; b < 4; ++b)
#pragma unroll
            for (int i = 0; i < 4; ++i) acc[a][b][i] = 0.f;

    // f32-path X prefetch registers (2 k-rows x 8 pixels), kc=0 preload
    f32x4 rA, rB, rC, rD;
    if (!bf) {
        const float* xp = (const float*)Xg_ + (size_t)(2 * r) * P + p0 + g * 8;
        rA = *(const f32x4*)xp;
        rB = *(const f32x4*)(xp + 4);
        rC = *(const f32x4*)(xp + P);
        rD = *(const f32x4*)(xp + P + 4);
    }

    for (int kc = 0; kc < 4; ++kc) {
        // ---- A: async-stage 32 KB for this kc; drains at the leading barrier.
        // Issued at loop top (right after prev trailing barrier -> WAR-safe),
        // latency overlaps the B staging below. ----
#pragma unroll
        for (int j = 0; j < 8; ++j) {
            __builtin_amdgcn_global_load_lds(
                (const __attribute__((address_space(1))) void*)(wsrc + j * 8192 + kc * 64),
                (__attribute__((address_space(3))) void*)(ldsA + j * 4096),
                16, 0, 0);
        }

        if (bf) {
            // ---- insurance path: bf16 input, load+pack in-loop ----
            const u16* xp = (const u16*)Xg_ + (size_t)(2 * r + kc * 64) * P + p0 + g * 8;
            const uint4 v0 = *(const uint4*)xp;
            const uint4 v1 = *(const uint4*)(xp + P);
            const uint32_t e0[4] = {v0.x, v0.y, v0.z, v0.w};
            const uint32_t e1[4] = {v1.x, v1.y, v1.z, v1.w};
#pragma unroll
            for (int d = 0; d < 4; ++d) {
                const float f00 = bfbits2f(e0[d] & 0xFFFFu), f01 = bfbits2f(e0[d] >> 16);
                const float f10 = bfbits2f(e1[d] & 0xFFFFu), f11 = bfbits2f(e1[d] >> 16);
                ssq[2 * d]     += f00 * f00 + f10 * f10;
                ssq[2 * d + 1] += f01 * f01 + f11 * f11;
                const uint32_t d0 = (e0[d] & 0xFFFFu) | (e1[d] << 16);
                const uint32_t d1 = (e0[d] >> 16) | (e1[d] & 0xFFFF0000u);
                const int pj0 = g * 8 + 2 * d, pj1 = pj0 + 1;
                *(uint32_t*)(sB + pj0 * 128 + (((r >> 2) ^ (pj0 & 7) ^ g) * 16) + (r & 3) * 4) = d0;
                *(uint32_t*)(sB + pj1 * 128 + (((r >> 2) ^ (pj1 & 7) ^ g) * 16) + (r & 3) * 4) = d1;
            }
        } else {
            // ---- f32 path: consume prefetched regs (ssq + pack + swizzled write) ----
            const float f0[8] = {rA[0], rA[1], rA[2], rA[3], rB[0], rB[1], rB[2], rB[3]};
            const float f1[8] = {rC[0], rC[1], rC[2], rC[3], rD[0], rD[1], rD[2], rD[3]};
#pragma unroll
            for (int j = 0; j < 8; ++j) {
                ssq[j] += f0[j] * f0[j] + f1[j] * f1[j];
                const int pix = g * 8 + j;
                *(uint32_t*)(sB + pix * 128 + (((r >> 2) ^ (pix & 7) ^ g) * 16) + (r & 3) * 4) =
                    pack2(f0[j], f1[j]);
            }
        }
        __syncthreads();   // sA gloads complete + sB writes visible

        // ---- T14: issue next kc's X loads now; they drain at the TRAILING
        //      barrier, fully overlapped by the MFMA phase. ----
        if (!bf && kc < 3) {
            const float* xp = (const float*)Xg_ + (size_t)(2 * r + (kc + 1) * 64) * P + p0 + g * 8;
            rA = *(const f32x4*)xp;
            rB = *(const f32x4*)(xp + 4);
            rC = *(const f32x4*)(xp + P);
            rD = *(const f32x4*)(xp + P + 4);
        }

        // ---- MFMA: 2 K=32 steps; wave tile 64 classes x 64 pixels ----
#pragma unroll
        for (int kk = 0; kk < 2; ++kk) {
            bf16x8 af[4], bfr[4];
#pragma unroll
            for (int tm = 0; tm < 4; ++tm) {
                const int row = w * 64 + tm * 16 + m16;
                af[tm] = *(const bf16x8*)(sA + row * 128 + (((kk * 4 + quad) ^ (row & 7)) * 16));
            }
#pragma unroll
            for (int tn = 0; tn < 4; ++tn) {
                const int pix = tn * 16 + m16;
                bfr[tn] = *(const bf16x8*)(sB + pix * 128 +
                           (((kk * 4 + quad) ^ (pix & 7) ^ (pix >> 3)) * 16));
            }
#pragma unroll
            for (int tm = 0; tm < 4; ++tm)
#pragma unroll
                for (int tn = 0; tn < 4; ++tn)
                    acc[tm][tn] = __builtin_amdgcn_mfma_f32_16x16x32_bf16(
                        af[tm], bfr[tn], acc[tm][tn], 0, 0, 0);
        }
        __syncthreads();   // protects sA/sB rewrite; drains B prefetch
    }

    // ---- epilogue: x-norms via LDS transpose-reduce (reuse smem_) ----
    float* xs   = (float*)sA;    // [32][64] partial ssq
    float* xinv = (float*)sB;    // [64]
#pragma unroll
    for (int j = 0; j < 8; ++j) xs[r * 64 + g * 8 + j] = ssq[j];
    __syncthreads();
    if (t < 64) {
        float sx = 0.f;
#pragma unroll
        for (int rr = 0; rr < 32; ++rr) sx += xs[rr * 64 + t];
        xinv[t] = 1.0f / fmaxf(sqrtf(sx), 1e-8f);
    }
    __syncthreads();

    // ---- scaled f32 store. class = w*64+tm*16+quad*4+i ; pixel = p0+tn*16+m16 ----
    float inv4[4];
#pragma unroll
    for (int tn = 0; tn < 4; ++tn) inv4[tn] = xinv[tn * 16 + m16];
#pragma unroll
    for (int tm = 0; tm < 4; ++tm) {
        const int cbase = w * 64 + tm * 16 + quad * 4;
        const f32x4 rs4 = *(const f32x4*)(rs_ws + cbase);
#pragma unroll
        for (int tn = 0; tn < 4; ++tn) {
#pragma unroll
            for (int i = 0; i < 4; ++i) {
                Og[(size_t)(cbase + i) * P + p0 + tn * 16 + m16] =
                    acc[tm][tn][i] * rs4[i] * inv4[tn];
            }
        }
    }
}

extern "C" void kernel_launch(void* const* d_in, const int* in_sizes, int n_in,
                              void* d_out, int out_size, void* d_ws, size_t ws_size,
                              hipStream_t stream) {
    (void)out_size; (void)ws_size;
    const void* X = d_in[0];
    const void* W = d_in[1];
    const void* S = d_in[2];
    for (int i = 0; i < n_in; ++i) {
        if (in_sizes[i] == 256 * 65536) X = d_in[i];
        else if (in_sizes[i] == 256 * 256) W = d_in[i];
        else if (in_sizes[i] == 256)      S = d_in[i];
    }
    float* rs  = (float*)d_ws;
    u16*   wbf = (u16*)((char*)d_ws + 1024);   // 128 KB bf16 W image
    coshead_prep<<<dim3(256), dim3(64), 0, stream>>>(X, W, S, rs, wbf);
    coshead_gemm<<<dim3(1024), dim3(256), 0, stream>>>(X, wbf, rs, (float*)d_out);
}